// Round 1
// baseline (786.624 us; speedup 1.0000x reference)
//
#include <hip/hip_runtime.h>

// HetConv2d: x[16,64,256,256] f32; per (i,j): 3x3 kernel if (j-i)%32==0 else 1x1.
// y[n,i,h,w] = b[i] + sum_j w1[i,j]*x[j,h,w]  (masked pairs cancelled via center tap)
//            + sum_{jm in {i&31,(i&31)+32}} 3x3(w3[i,jm], x[jm])  with center tap (w3-w1).

#define CCH 64
#define HH  256
#define WW  256
#define TH  4
#define TW  64
#define LROW 68                 // padded LDS row (elems)
#define LPLANE (6 * LROW)       // elems per channel plane

__device__ __forceinline__ unsigned short f2bf(float f) {
    unsigned int u = __float_as_uint(f);
    u += 0x7FFFu + ((u >> 16) & 1u);   // RNE
    return (unsigned short)(u >> 16);
}
__device__ __forceinline__ float bf2f(unsigned short u) {
    return __uint_as_float(((unsigned int)u) << 16);
}

__global__ __launch_bounds__(256, 3) void hetconv_kernel(
    const float* __restrict__ x, const float* __restrict__ w3,
    const float* __restrict__ w1, const float* __restrict__ b,
    float* __restrict__ y)
{
    __shared__ unsigned short s_x[CCH][TH + 2][LROW];   // 64*6*68*2 = 52224 B

    const int tx = threadIdx.x;           // 0..63
    const int ty = threadIdx.y;           // 0..3
    const int tid = ty * TW + tx;
    const int n  = blockIdx.z;
    const int h0 = blockIdx.y * TH;
    const int w0 = blockIdx.x * TW;
    const int h  = h0 + ty;
    const int w  = w0 + tx;

    const size_t nbase = (size_t)n * CCH * HH * WW;

    // ---------- interior staging (also fills per-thread f32 center values) ----
    float xv[CCH];
    {
        const float* xp = x + nbase + (size_t)h * WW + w;
        #pragma unroll
        for (int j = 0; j < CCH; ++j) {
            float v = xp[(size_t)j * HH * WW];
            xv[j] = v;
            s_x[j][ty + 1][tx + 1] = f2bf(v);
        }
    }

    // ---------- halo staging ----------
    {
        int lr = 0, lc = 0;
        bool active = true;
        if      (tid < 66)  { lr = 0;         lc = tid;        }
        else if (tid < 132) { lr = TH + 1;    lc = tid - 66;   }
        else if (tid < 136) { lr = tid - 131; lc = 0;          }
        else if (tid < 140) { lr = tid - 135; lc = TW + 1;     }
        else                { active = false; }

        if (active) {
            const int gy = h0 + lr - 1;
            const int gx = w0 + lc - 1;
            const bool inb = (gy >= 0) && (gy < HH) && (gx >= 0) && (gx < WW);
            const int cgy = inb ? gy : 0;
            const int cgx = inb ? gx : 0;
            const float* hp = x + nbase + (size_t)cgy * WW + cgx;
            unsigned short* lp = &s_x[0][lr][lc];
            #pragma unroll 4
            for (int j = 0; j < CCH; ++j) {
                float v = inb ? hp[(size_t)j * HH * WW] : 0.0f;
                lp[j * LPLANE] = f2bf(v);
            }
        }
    }
    __syncthreads();

    // ---------- compute ----------
    float* yp = y + nbase + (size_t)h * WW + w;

    #pragma unroll 2
    for (int i = 0; i < CCH; ++i) {
        const float* w1r = w1 + i * CCH;

        float a0 = b[i];
        float a1 = 0.0f;
        #pragma unroll
        for (int j = 0; j < CCH; j += 2) {
            a0 += xv[j]     * w1r[j];
            a1 += xv[j + 1] * w1r[j + 1];
        }

        const int jm = i & 31;
        const unsigned short* pa = &s_x[jm][ty][tx];       // taps rows ty..ty+2
        const unsigned short* pb = &s_x[jm + 32][ty][tx];
        const float* w3a = w3 + (size_t)(i * CCH + jm) * 9;
        const float* w3b = w3 + (size_t)(i * CCH + jm + 32) * 9;
        const float ca = w1r[jm];
        const float cb = w1r[jm + 32];

        #pragma unroll
        for (int t = 0; t < 9; ++t) {
            const int dy = t / 3, dx = t % 3;
            float wa = w3a[t];
            float wb = w3b[t];
            if (t == 4) { wa -= ca; wb -= cb; }   // cancel the masked 1x1 terms
            const float va = bf2f(pa[dy * LROW + dx]);
            const float vb = bf2f(pb[dy * LROW + dx]);
            a0 += va * wa;
            a1 += vb * wb;
        }

        yp[(size_t)i * HH * WW] = a0 + a1;
    }
}

extern "C" void kernel_launch(void* const* d_in, const int* in_sizes, int n_in,
                              void* d_out, int out_size, void* d_ws, size_t ws_size,
                              hipStream_t stream) {
    (void)in_sizes; (void)n_in; (void)d_ws; (void)ws_size; (void)out_size;
    const float* x  = (const float*)d_in[0];
    const float* w3 = (const float*)d_in[1];
    const float* w1 = (const float*)d_in[2];
    const float* b  = (const float*)d_in[3];
    float* y = (float*)d_out;

    dim3 grid(WW / TW, HH / TH, 16);
    dim3 block(TW, TH, 1);
    hipLaunchKernelGGL(hetconv_kernel, grid, block, 0, stream, x, w3, w1, b, y);
}

// Round 2
// 264.495 us; speedup vs baseline: 2.9741x; 2.9741x over previous
//
#include <hip/hip_runtime.h>

// HetConv2d via MFMA (bf16 inputs/weights, f32 accum).
// y[n,i,p] = b[i] + sum_j Wc[i,j] x[j,p] + sum_{t!=center} sum_{d in {0,32}}
//            w3[i,(i&31)+d,t] * x[(i&31)+d, p+shift_t]
// Wc[i,j] = (j==i mod 32) ? w3[i,j,1,1] : w1[i,j]   (center handled exactly)
//
// MFMA 16x16x32: A[m][k]: m=lane&15, k=(lane>>4)*8+e ; B[k][n]: n=lane&15,
// same k map ; D: col=lane&15, row=(lane>>4)*4+reg.
// Off-center taps pack K=32 as (d,jj): k -> channel (pair*16 + (k&15) + 32*(k>>4)),
// A has exactly one nonzero per lane at e=(l&15)&7, valid iff ((l>>4)&1)==((l&15)>>3).

#define HH 256
#define WW 256
#define CCH 64
#define HW (HH * WW)
#define TH 4
#define TW 32
#define HROWS (TH + 2)          // 6
#define HCOLS (TW + 2)          // 34
#define NPIX (HROWS * HCOLS)    // 204

typedef __attribute__((ext_vector_type(8))) short bf16x8;
typedef __attribute__((ext_vector_type(4))) float f32x4;

__device__ __forceinline__ unsigned short f2bf(float f) {
    unsigned int u = __float_as_uint(f);
    u += 0x7FFFu + ((u >> 16) & 1u);   // RNE
    return (unsigned short)(u >> 16);
}

// byte offset of (pixel p, channel c) in the swizzled LDS tile
__device__ __forceinline__ int lds_off(int p, int c) {
    return ((p << 7) + (c << 1)) ^ ((p & 7) << 4);
}

__global__ __launch_bounds__(256, 2) void hetconv_mfma(
    const float* __restrict__ x, const float* __restrict__ w3,
    const float* __restrict__ w1, const float* __restrict__ b,
    float* __restrict__ y)
{
    __shared__ __align__(16) unsigned short s_x[NPIX * CCH];   // 26112 B

    const int tid  = threadIdx.x;
    const int lane = tid & 63;
    const int wv   = tid >> 6;          // 0..3
    const int l15  = lane & 15;
    const int lq   = lane >> 4;         // 0..3
    const int pair  = wv & 1;           // channel group: {0,32} or {16,48}
    const int trow0 = (wv >> 1) * 2;    // rows {0,1} or {2,3}

    const int n  = blockIdx.z;
    const int h0 = blockIdx.y * TH;
    const int w0 = blockIdx.x * TW;
    const size_t nbase = (size_t)n * CCH * HW;

    // ---------------- stage x tile (f32 -> bf16, pixel-major, swizzled) ------
    if (tid < NPIX) {
        const int r = tid / HCOLS;
        const int c = tid - r * HCOLS;
        const int gh = h0 + r - 1;
        const int gw = w0 + c - 1;
        const bool inb = ((unsigned)gh < HH) && ((unsigned)gw < WW);
        const float* xp = x + nbase + (size_t)(inb ? gh : 0) * WW + (inb ? gw : 0);
        char* lbase = (char*)s_x;
        #pragma unroll 4
        for (int c4 = 0; c4 < CCH; c4 += 4) {
            float v0 = inb ? xp[(size_t)(c4 + 0) * HW] : 0.0f;
            float v1 = inb ? xp[(size_t)(c4 + 1) * HW] : 0.0f;
            float v2 = inb ? xp[(size_t)(c4 + 2) * HW] : 0.0f;
            float v3 = inb ? xp[(size_t)(c4 + 3) * HW] : 0.0f;
            uint2 pk;
            pk.x = (unsigned)f2bf(v0) | ((unsigned)f2bf(v1) << 16);
            pk.y = (unsigned)f2bf(v2) | ((unsigned)f2bf(v3) << 16);
            *(uint2*)(lbase + lds_off(tid, c4)) = pk;
        }
    }

    // ---------------- build A fragments (weights, per wave) ------------------
    const int ia = pair * 16 + l15;        // mtile a: out channel
    const int ib = ia + 32;                // mtile b

    // center: dense Wc, k = kh*32 + lq*8 + e
    bf16x8 fc[2][2];                       // [mt][kh]
    #pragma unroll
    for (int mt = 0; mt < 2; ++mt) {
        const int i = mt ? ib : ia;
        #pragma unroll
        for (int kh = 0; kh < 2; ++kh) {
            const int c0 = kh * 32 + lq * 8;
            bf16x8 v;
            #pragma unroll
            for (int e = 0; e < 8; ++e) {
                const int j = c0 + e;
                const float wval = (((j ^ i) & 31) == 0)
                                   ? w3[((size_t)i * CCH + j) * 9 + 4]
                                   : w1[(size_t)i * CCH + j];
                v[e] = (short)f2bf(wval);
            }
            fc[mt][kh] = v;
        }
    }

    // off-center taps: one nonzero per lane (or none)
    const bool avalid = ((lq & 1) == (l15 >> 3));
    const int  epos   = l15 & 7;
    const int  jcol   = pair * 16 + l15 + 32 * (lane >> 5);

    bf16x8 ft[2][8];                       // [mt][tap (skipping center)]
    #pragma unroll
    for (int mt = 0; mt < 2; ++mt) {
        const int i = mt ? ib : ia;
        const float* wp = w3 + ((size_t)i * CCH + jcol) * 9;
        int ti = 0;
        #pragma unroll
        for (int t = 0; t < 9; ++t) {
            if (t == 4) continue;
            const float val = avalid ? wp[t] : 0.0f;
            const short bv = (short)f2bf(val);
            bf16x8 f;
            #pragma unroll
            for (int e2 = 0; e2 < 8; ++e2) f[e2] = (e2 == epos) ? bv : (short)0;
            ft[mt][ti] = f;
            ++ti;
        }
    }

    // bias (per output row this lane owns)
    float bias_[2][4];
    #pragma unroll
    for (int mt = 0; mt < 2; ++mt) {
        const int chb = (mt ? 32 : 0) + pair * 16 + lq * 4;
        #pragma unroll
        for (int r = 0; r < 4; ++r) bias_[mt][r] = b[chb + r];
    }

    __syncthreads();

    // ---------------- compute -----------------------------------------------
    const char* lbase = (const char*)s_x;
    const int c0t = pair * 16 + (lq & 1) * 8 + 32 * (lane >> 5);  // tap B channels

    f32x4 acc[4][2];
    #pragma unroll
    for (int g = 0; g < 4; ++g)
        #pragma unroll
        for (int mt = 0; mt < 2; ++mt)
            acc[g][mt] = (f32x4){0.f, 0.f, 0.f, 0.f};

    #pragma unroll
    for (int g = 0; g < 4; ++g) {
        const int row = trow0 + (g >> 1);       // tile row 0..3
        const int gc  = (g & 1) * 16;           // pixel-group col base

        // center tap (dy=1, dx=1), dense K=64
        {
            const int p = (row + 1) * HCOLS + gc + l15 + 1;
            #pragma unroll
            for (int kh = 0; kh < 2; ++kh) {
                const bf16x8 bf = *(const bf16x8*)(lbase + lds_off(p, kh * 32 + lq * 8));
                acc[g][0] = __builtin_amdgcn_mfma_f32_16x16x32_bf16(fc[0][kh], bf, acc[g][0], 0, 0, 0);
                acc[g][1] = __builtin_amdgcn_mfma_f32_16x16x32_bf16(fc[1][kh], bf, acc[g][1], 0, 0, 0);
            }
        }

        // 8 off-center taps, packed K=32
        int ti = 0;
        #pragma unroll
        for (int t = 0; t < 9; ++t) {
            if (t == 4) continue;
            const int dy = t / 3, dx = t % 3;
            const int p = (row + dy) * HCOLS + gc + l15 + dx;
            const bf16x8 bf = *(const bf16x8*)(lbase + lds_off(p, c0t));
            acc[g][0] = __builtin_amdgcn_mfma_f32_16x16x32_bf16(ft[0][ti], bf, acc[g][0], 0, 0, 0);
            acc[g][1] = __builtin_amdgcn_mfma_f32_16x16x32_bf16(ft[1][ti], bf, acc[g][1], 0, 0, 0);
            ++ti;
        }
    }

    // ---------------- store --------------------------------------------------
    #pragma unroll
    for (int g = 0; g < 4; ++g) {
        const int row = trow0 + (g >> 1);
        const int gc  = (g & 1) * 16;
        const int gh  = h0 + row;
        const int gw  = w0 + gc + l15;
        #pragma unroll
        for (int mt = 0; mt < 2; ++mt) {
            const int chb = (mt ? 32 : 0) + pair * 16 + lq * 4;
            #pragma unroll
            for (int r = 0; r < 4; ++r) {
                y[nbase + (size_t)(chb + r) * HW + (size_t)gh * WW + gw] =
                    acc[g][mt][r] + bias_[mt][r];
            }
        }
    }
}

extern "C" void kernel_launch(void* const* d_in, const int* in_sizes, int n_in,
                              void* d_out, int out_size, void* d_ws, size_t ws_size,
                              hipStream_t stream) {
    (void)in_sizes; (void)n_in; (void)d_ws; (void)ws_size; (void)out_size;
    const float* x  = (const float*)d_in[0];
    const float* w3 = (const float*)d_in[1];
    const float* w1 = (const float*)d_in[2];
    const float* b  = (const float*)d_in[3];
    float* y = (float*)d_out;

    dim3 grid(WW / TW, HH / TH, 16);   // 8 x 64 x 16
    dim3 block(256, 1, 1);
    hipLaunchKernelGGL(hetconv_mfma, grid, block, 0, stream, x, w3, w1, b, y);
}